// Round 8
// baseline (126.398 us; speedup 1.0000x reference)
//
#include <hip/hip_runtime.h>
#include <hip/hip_bf16.h>

typedef __attribute__((ext_vector_type(8))) short short8;   // 8 bf16 (MFMA A/B frag)
typedef __attribute__((ext_vector_type(4))) float floatx4;  // MFMA C/D frag
typedef unsigned int u32;

#define D_DIM 256
#define TCOLS 64      // B-tile width (cols per tile)
#define TILES 8       // tiles per block -> 512 cols/block
#define IDX_BITS 0x1FFFu      // 13-bit index payload (N=M=8192)
#define VAL_MASK 0xFFFFE000u  // truncated value bits (sim+2 positive -> raw bits monotone)

// ---------- helpers ----------

__device__ inline unsigned short f2bf_rne(float f) {
  u32 u = __float_as_uint(f);
  u32 r = (u + 0x7FFFu + ((u >> 16) & 1u)) >> 16;
  return (unsigned short)r;
}

__device__ inline u32 umax(u32 a, u32 b) { return a > b ? a : b; }

__device__ inline void async_ld16(const void* g, void* l) {
  __builtin_amdgcn_global_load_lds((const __attribute__((address_space(1))) void*)g,
                                   (__attribute__((address_space(3))) void*)l, 16, 0, 0);
}

// ---------- kernels ----------

// Both inputs: [256][8192] f32 -> [8192][256] bf16; z selects input.
__global__ __launch_bounds__(256) void transpose_cast(const float* __restrict__ d0,
                                                      const float* __restrict__ d1,
                                                      unsigned short* __restrict__ At,
                                                      unsigned short* __restrict__ Bt,
                                                      int C, u32* __restrict__ best, int init_n) {
  const float* src = blockIdx.z ? d1 : d0;
  unsigned short* dst = blockIdx.z ? Bt : At;
  const int tid = threadIdx.x;
  const int d = blockIdx.x * 64 + (tid & 63);     // descriptor index
  const int chunk = blockIdx.y * 4 + (tid >> 6);  // 8-feature chunk, 0..31
  const int f0 = chunk * 8;
  float v[8];
#pragma unroll
  for (int u = 0; u < 8; ++u) v[u] = src[(size_t)(f0 + u) * C + d];
  short8 o;
#pragma unroll
  for (int u = 0; u < 8; ++u) o[u] = (short)f2bf_rne(v[u]);
  *(short8*)(dst + (size_t)d * D_DIM + f0) = o;
  if (blockIdx.z == 0 && blockIdx.y == 0) {
    int i = blockIdx.x * 256 + tid;
    if (i < init_n) best[i] = 0u;
  }
}

// Full-K-in-registers GEMM + fused argmax.
// 512-thread blocks: 8 waves x 64 rows = 512 rows/block, TILES x 64 cols.
// One block per CU (grid=256) forces 2 waves/SIMD in-block; per-wave regs are
// the R3-proven ~240 (af 128 + acc 64 AGPR + rbk 16 + misc) under the 256 cap
// implied by 512-thread blocks. 64 rows/wave halves LDS B-frag traffic per
// FLOP vs R7 (data-movement/FLOP = 1/2(1/rows+1/cols)) -> MFMA-bound.
// acc init = +2.0: outputs sim+2 in [1,3), positive -> raw IEEE bits monotone
// under unsigned compare -> no fmap in epilogue.
__global__ __launch_bounds__(512) void gemm_reduce(const unsigned short* __restrict__ At,
                                                   const unsigned short* __restrict__ Bt,
                                                   u32* __restrict__ best01,
                                                   u32* __restrict__ best10) {
  __shared__ alignas(16) unsigned short sB[2][TCOLS * D_DIM];  // 2 x 32 KB
  __shared__ u32 ldsCol[2][TCOLS];                             // dbuf: 1 barrier/tile

  const int tid  = threadIdx.x;
  const int wave = tid >> 6;
  const int lane = tid & 63;
  const int quad = lane >> 4;
  const int l15  = lane & 15;
  const int n0   = blockIdx.x * 512;
  const int mg0  = blockIdx.y * (TILES * TCOLS);
  const int rbase = n0 + wave * 64;   // 64 rows per wave

  if (tid < 2 * TCOLS) ldsCol[tid >> 6][tid & 63] = 0u;

  // stage B tile 0 into buf 0 (LDS dest = uniform base + tid*16 — required)
  {
    const unsigned short* src = Bt + (size_t)mg0 * D_DIM;
#pragma unroll
    for (int c = 0; c < 4; ++c) {     // 2048 slots / 512 threads
      int slot = c * 512 + tid;
      int r = slot >> 5, cc = slot & 31;
      int ccg = (cc & 24) | ((cc ^ r) & 7);  // XOR-swizzle kills frag-read conflicts
      async_ld16(src + (size_t)r * D_DIM + ccg * 8, (unsigned short*)sB[0] + slot * 8);
    }
  }

  // A fragments: wave's 64 rows x full K=256, straight from global (once).
  short8 af[4][8];
#pragma unroll
  for (int t = 0; t < 4; ++t)
#pragma unroll
    for (int kc = 0; kc < 8; ++kc)
      af[t][kc] = *(const short8*)(At + (size_t)(rbase + t * 16 + l15) * D_DIM + kc * 32 + quad * 8);

  u32 rbk[16];  // running row-argmax keys (16 rows per lane)
#pragma unroll
  for (int s = 0; s < 16; ++s) rbk[s] = 0u;

  __syncthreads();  // drains vmcnt: B0 staged; ldsCol init visible

  for (int mt = 0; mt < TILES; ++mt) {
    const int m0 = mg0 + mt * TCOLS;
    if (mt + 1 < TILES) {  // prefetch next B tile — latency hides under MFMA
      const unsigned short* src = Bt + (size_t)(m0 + TCOLS) * D_DIM;
      unsigned short* dstb = (unsigned short*)sB[(mt + 1) & 1];
#pragma unroll
      for (int c = 0; c < 4; ++c) {
        int slot = c * 512 + tid;
        int r = slot >> 5, cc = slot & 31;
        int ccg = (cc & 24) | ((cc ^ r) & 7);
        async_ld16(src + (size_t)r * D_DIM + ccg * 8, dstb + slot * 8);
      }
    }

    floatx4 acc[4][4];
#pragma unroll
    for (int i = 0; i < 4; ++i)
#pragma unroll
      for (int j = 0; j < 4; ++j)
        acc[i][j] = (floatx4){2.0f, 2.0f, 2.0f, 2.0f};  // bias: outputs = sim+2 > 0

    const unsigned short* sb = (const unsigned short*)sB[mt & 1];
#pragma unroll
    for (int kc = 0; kc < 8; ++kc) {
      short8 bfr[4];
#pragma unroll
      for (int j = 0; j < 4; ++j) {
        int c2 = j * 16 + l15;
        int ch = kc * 4 + quad;
        int chg = (ch & 24) | ((ch ^ c2) & 7);  // un-swizzle
        bfr[j] = *(const short8*)(sb + c2 * D_DIM + chg * 8);
      }
#pragma unroll
      for (int i = 0; i < 4; ++i)
#pragma unroll
        for (int j = 0; j < 4; ++j)
          acc[i][j] = __builtin_amdgcn_mfma_f32_16x16x32_bf16(af[i][kc], bfr[j], acc[i][j], 0, 0, 0);
    }

    // ---- epilogue. C/D map: col = j*16 + l15, row = i*16 + quad*4 + r
    u32 cb[4] = {0u, 0u, 0u, 0u};
    u32 colpay[4];
#pragma unroll
    for (int j = 0; j < 4; ++j) colpay[j] = (~(u32)(m0 + j * 16 + l15)) & IDX_BITS;
#pragma unroll
    for (int i = 0; i < 4; ++i)
#pragma unroll
      for (int r = 0; r < 4; ++r) {
        u32 rowpay = (~(u32)(rbase + i * 16 + quad * 4 + r)) & IDX_BITS;
        u32 rb = rbk[i * 4 + r];
#pragma unroll
        for (int j = 0; j < 4; ++j) {
          u32 u = __float_as_uint(acc[i][j][r]) & VAL_MASK;  // positive -> monotone
          rb = umax(rb, u | colpay[j]);
          cb[j] = umax(cb[j], u | rowpay);
        }
        rbk[i * 4 + r] = rb;
      }
    // col-argmax: butterfly over the 4 quads (rows), then LDS combine of 8 waves
#pragma unroll
    for (int j = 0; j < 4; ++j) {
      u32 b = cb[j];
      b = umax(b, (u32)__shfl_xor((int)b, 16, 64));
      b = umax(b, (u32)__shfl_xor((int)b, 32, 64));
      if (quad == 0) atomicMax(&ldsCol[mt & 1][j * 16 + l15], b);
    }
    __syncthreads();  // col atomics + prev reset visible; vmcnt drained -> next B ready
    if (tid < TCOLS) {
      u32 g = ldsCol[mt & 1][tid];
      ldsCol[mt & 1][tid] = 0u;  // next use is tile mt+2; tile mt+1's barrier orders it
      atomicMax(&best10[m0 + tid], g);
    }
  }

  // ---- final row reduction: butterfly over l15, one atomic per row
#pragma unroll
  for (int i = 0; i < 4; ++i)
#pragma unroll
    for (int r = 0; r < 4; ++r) {
      u32 b = rbk[i * 4 + r];
      b = umax(b, (u32)__shfl_xor((int)b, 1, 64));
      b = umax(b, (u32)__shfl_xor((int)b, 2, 64));
      b = umax(b, (u32)__shfl_xor((int)b, 4, 64));
      b = umax(b, (u32)__shfl_xor((int)b, 8, 64));
      if (l15 == 0) atomicMax(&best01[rbase + i * 16 + quad * 4 + r], b);
    }
}

__global__ void finalize(const u32* __restrict__ best01, const u32* __restrict__ best10,
                         float* __restrict__ out, int N) {
  int n = blockIdx.x * blockDim.x + threadIdx.x;
  if (n >= N) return;
  u32 k = best01[n];
  int idx01 = (int)((~k) & IDX_BITS);
  float sim = __uint_as_float(k & VAL_MASK) - 2.0f;  // undo +2 bias
  int idx10 = (int)((~best10[idx01]) & IDX_BITS);
  float dist = 2.0f - 2.0f * sim;             // squared L2 for unit vectors
  bool ok = (idx10 == n) && (dist <= 0.64f);  // mutual NN + thresh^2
  out[n]     = ok ? (float)idx01 : -1.0f;
  out[N + n] = ok ? 1.5f - sim : 0.0f;        // (dist+1)/2
}

// ---------- launcher ----------

extern "C" void kernel_launch(void* const* d_in, const int* in_sizes, int n_in,
                              void* d_out, int out_size, void* d_ws, size_t ws_size,
                              hipStream_t stream) {
  (void)n_in; (void)out_size; (void)ws_size;
  const float* d0 = (const float*)d_in[0];  // [256][N]
  const float* d1 = (const float*)d_in[1];  // [256][M]
  const int N = in_sizes[0] / D_DIM;        // 8192
  const int M = in_sizes[1] / D_DIM;        // 8192

  u32* best01 = (u32*)d_ws;                            // N u32
  u32* best10 = best01 + N;                            // M u32
  unsigned short* At = (unsigned short*)(best10 + M);  // [N][256] bf16
  unsigned short* Bt = At + (size_t)N * D_DIM;         // [M][256] bf16
  float* out = (float*)d_out;

  hipLaunchKernelGGL(transpose_cast, dim3(N / 64, 8, 2), dim3(256), 0, stream,
                     d0, d1, At, Bt, N, best01, N + M);
  hipLaunchKernelGGL(gemm_reduce, dim3(N / 512, M / (TILES * TCOLS)), dim3(512), 0, stream,
                     At, Bt, best01, best10);
  hipLaunchKernelGGL(finalize, dim3(N / 256), dim3(256), 0, stream, best01, best10, out, N);
}

// Round 9
// 124.106 us; speedup vs baseline: 1.0185x; 1.0185x over previous
//
#include <hip/hip_runtime.h>
#include <hip/hip_bf16.h>

typedef __attribute__((ext_vector_type(8))) short short8;   // 8 bf16 (MFMA A/B frag)
typedef __attribute__((ext_vector_type(4))) float floatx4;  // MFMA C/D frag
typedef unsigned int u32;

#define D_DIM 256
#define TCOLS 64      // B-tile width (cols per tile)
#define TILES 8       // tiles per block -> 512 cols/block -> grid 32x16 = 2 blocks/CU
#define IDX_BITS 0x1FFFu      // 13-bit index payload (N=M=8192)
#define VAL_MASK 0xFFFFE000u  // truncated value bits (sim+2 positive -> raw bits monotone)

// ---------- helpers ----------

__device__ inline unsigned short f2bf_rne(float f) {
  u32 u = __float_as_uint(f);
  u32 r = (u + 0x7FFFu + ((u >> 16) & 1u)) >> 16;
  return (unsigned short)r;
}

__device__ inline u32 umax(u32 a, u32 b) { return a > b ? a : b; }

__device__ inline void async_ld16(const void* g, void* l) {
  __builtin_amdgcn_global_load_lds((const __attribute__((address_space(1))) void*)g,
                                   (__attribute__((address_space(3))) void*)l, 16, 0, 0);
}

// ---------- kernels ----------

// B only: [256][8192] f32 -> [8192][256] bf16. Coalesced 256B reads/wave,
// 16B short8 stores. Folds best-array init. (A is cast inline in the GEMM.)
__global__ __launch_bounds__(256) void transpose_cast(const float* __restrict__ src,
                                                      unsigned short* __restrict__ dst, int C,
                                                      u32* __restrict__ best, int init_n) {
  const int tid = threadIdx.x;
  const int d = blockIdx.x * 64 + (tid & 63);     // descriptor index
  const int chunk = blockIdx.y * 4 + (tid >> 6);  // 8-feature chunk, 0..31
  const int f0 = chunk * 8;
  float v[8];
#pragma unroll
  for (int u = 0; u < 8; ++u) v[u] = src[(size_t)(f0 + u) * C + d];
  short8 o;
#pragma unroll
  for (int u = 0; u < 8; ++u) o[u] = (short)f2bf_rne(v[u]);
  *(short8*)(dst + (size_t)d * D_DIM + f0) = o;
  if (blockIdx.y == 0) {
    int i = blockIdx.x * 256 + tid;  // 128 x 256 = 32768 >= 16384
    if (i < init_n) best[i] = 0u;
  }
}

// Full-K-in-registers GEMM + fused argmax. 256 threads, 4 waves x 64 rows.
// LDS is EXACTLY 65536 B (m132: 64 KB LDS co-schedules 2 blocks/CU; R6's
// 66048 B did not) — ldsCol removed, col-argmax goes straight to global
// atomics. Register shape is the R3-proven no-spill ~240 under (256,1).
// A-frags are loaded from the ORIGINAL f32 [256][N] layout and cast inline
// (64B-coalesced per quad; one-time per block; L3-served on re-reads).
// acc init = +2.0: outputs sim+2 in [1,3), positive -> raw IEEE bits
// monotone under unsigned compare -> no fmap in the epilogue.
__global__ __launch_bounds__(256, 1) void gemm_reduce(const float* __restrict__ A,
                                                      const unsigned short* __restrict__ Bt,
                                                      u32* __restrict__ best01,
                                                      u32* __restrict__ best10,
                                                      int N) {
  __shared__ alignas(16) unsigned short sB[2][TCOLS * D_DIM];  // 2 x 32 KB = 65536 B

  const int tid  = threadIdx.x;
  const int wave = tid >> 6;
  const int lane = tid & 63;
  const int quad = lane >> 4;
  const int l15  = lane & 15;
  const int n0   = blockIdx.x * 256;
  const int mg0  = blockIdx.y * (TILES * TCOLS);
  const int rbase = n0 + wave * 64;   // 64 rows per wave

  // stage B tile 0 into buf 0 (LDS dest = uniform base + tid*16 — required)
  {
    const unsigned short* src = Bt + (size_t)mg0 * D_DIM;
#pragma unroll
    for (int c = 0; c < 8; ++c) {     // 2048 slots / 256 threads
      int slot = c * 256 + tid;
      int r = slot >> 5, cc = slot & 31;
      int ccg = (cc & 24) | ((cc ^ r) & 7);  // XOR-swizzle kills frag-read conflicts
      async_ld16(src + (size_t)r * D_DIM + ccg * 8, (unsigned short*)sB[0] + slot * 8);
    }
  }

  // A fragments: wave's 64 rows x full K=256 from f32 [256][N], cast to bf16.
  // Per (t,kc,u): 16 lanes (l15) read 16 consecutive f32 = 64B segments.
  short8 af[4][8];
#pragma unroll
  for (int t = 0; t < 4; ++t)
#pragma unroll
    for (int kc = 0; kc < 8; ++kc) {
      const int row = rbase + t * 16 + l15;
      const int kb = kc * 32 + quad * 8;
      short8 o;
#pragma unroll
      for (int u = 0; u < 8; ++u)
        o[u] = (short)f2bf_rne(A[(size_t)(kb + u) * N + row]);
      af[t][kc] = o;
    }

  u32 rbk[16];  // running row-argmax keys (16 rows per lane)
#pragma unroll
  for (int s = 0; s < 16; ++s) rbk[s] = 0u;

  __syncthreads();  // drains vmcnt: B0 staged

  for (int mt = 0; mt < TILES; ++mt) {
    const int m0 = mg0 + mt * TCOLS;
    if (mt + 1 < TILES) {  // prefetch next B tile — latency hides under MFMA
      const unsigned short* src = Bt + (size_t)(m0 + TCOLS) * D_DIM;
      unsigned short* dstb = (unsigned short*)sB[(mt + 1) & 1];
#pragma unroll
      for (int c = 0; c < 8; ++c) {
        int slot = c * 256 + tid;
        int r = slot >> 5, cc = slot & 31;
        int ccg = (cc & 24) | ((cc ^ r) & 7);
        async_ld16(src + (size_t)r * D_DIM + ccg * 8, dstb + slot * 8);
      }
    }

    floatx4 acc[4][4];
#pragma unroll
    for (int i = 0; i < 4; ++i)
#pragma unroll
      for (int j = 0; j < 4; ++j)
        acc[i][j] = (floatx4){2.0f, 2.0f, 2.0f, 2.0f};  // bias: outputs = sim+2 > 0

    const unsigned short* sb = (const unsigned short*)sB[mt & 1];
#pragma unroll
    for (int kc = 0; kc < 8; ++kc) {
      short8 bfr[4];
#pragma unroll
      for (int j = 0; j < 4; ++j) {
        int c2 = j * 16 + l15;
        int ch = kc * 4 + quad;
        int chg = (ch & 24) | ((ch ^ c2) & 7);  // un-swizzle
        bfr[j] = *(const short8*)(sb + c2 * D_DIM + chg * 8);
      }
#pragma unroll
      for (int i = 0; i < 4; ++i)
#pragma unroll
        for (int j = 0; j < 4; ++j)
          acc[i][j] = __builtin_amdgcn_mfma_f32_16x16x32_bf16(af[i][kc], bfr[j], acc[i][j], 0, 0, 0);
    }

    // ---- epilogue. C/D map: col = j*16 + l15, row = i*16 + quad*4 + r
    u32 cb[4] = {0u, 0u, 0u, 0u};
    u32 colpay[4];
#pragma unroll
    for (int j = 0; j < 4; ++j) colpay[j] = (~(u32)(m0 + j * 16 + l15)) & IDX_BITS;
#pragma unroll
    for (int i = 0; i < 4; ++i)
#pragma unroll
      for (int r = 0; r < 4; ++r) {
        u32 rowpay = (~(u32)(rbase + i * 16 + quad * 4 + r)) & IDX_BITS;
        u32 rb = rbk[i * 4 + r];
#pragma unroll
        for (int j = 0; j < 4; ++j) {
          u32 u = __float_as_uint(acc[i][j][r]) & VAL_MASK;  // positive -> monotone
          rb = umax(rb, u | colpay[j]);
          cb[j] = umax(cb[j], u | rowpay);
        }
        rbk[i * 4 + r] = rb;
      }
    // col-argmax: butterfly over the 4 quads, then DIRECT global atomics
#pragma unroll
    for (int j = 0; j < 4; ++j) {
      u32 b = cb[j];
      b = umax(b, (u32)__shfl_xor((int)b, 16, 64));
      b = umax(b, (u32)__shfl_xor((int)b, 32, 64));
      if (quad == 0) atomicMax(&best10[m0 + j * 16 + l15], b);
    }
    __syncthreads();  // all ds_reads of sb done; vmcnt drained -> next B ready
  }

  // ---- final row reduction: butterfly over l15, one atomic per row
#pragma unroll
  for (int i = 0; i < 4; ++i)
#pragma unroll
    for (int r = 0; r < 4; ++r) {
      u32 b = rbk[i * 4 + r];
      b = umax(b, (u32)__shfl_xor((int)b, 1, 64));
      b = umax(b, (u32)__shfl_xor((int)b, 2, 64));
      b = umax(b, (u32)__shfl_xor((int)b, 4, 64));
      b = umax(b, (u32)__shfl_xor((int)b, 8, 64));
      if (l15 == 0) atomicMax(&best01[rbase + i * 16 + quad * 4 + r], b);
    }
}

__global__ void finalize(const u32* __restrict__ best01, const u32* __restrict__ best10,
                         float* __restrict__ out, int N) {
  int n = blockIdx.x * blockDim.x + threadIdx.x;
  if (n >= N) return;
  u32 k = best01[n];
  int idx01 = (int)((~k) & IDX_BITS);
  float sim = __uint_as_float(k & VAL_MASK) - 2.0f;  // undo +2 bias
  int idx10 = (int)((~best10[idx01]) & IDX_BITS);
  float dist = 2.0f - 2.0f * sim;             // squared L2 for unit vectors
  bool ok = (idx10 == n) && (dist <= 0.64f);  // mutual NN + thresh^2
  out[n]     = ok ? (float)idx01 : -1.0f;
  out[N + n] = ok ? 1.5f - sim : 0.0f;        // (dist+1)/2
}

// ---------- launcher ----------

extern "C" void kernel_launch(void* const* d_in, const int* in_sizes, int n_in,
                              void* d_out, int out_size, void* d_ws, size_t ws_size,
                              hipStream_t stream) {
  (void)n_in; (void)out_size; (void)ws_size;
  const float* d0 = (const float*)d_in[0];  // [256][N]
  const float* d1 = (const float*)d_in[1];  // [256][M]
  const int N = in_sizes[0] / D_DIM;        // 8192
  const int M = in_sizes[1] / D_DIM;        // 8192

  u32* best01 = (u32*)d_ws;                            // N u32
  u32* best10 = best01 + N;                            // M u32
  unsigned short* Bt = (unsigned short*)(best10 + M);  // [M][256] bf16
  float* out = (float*)d_out;

  hipLaunchKernelGGL(transpose_cast, dim3(M / 64, 8), dim3(256), 0, stream,
                     d1, Bt, M, best01, N + M);
  hipLaunchKernelGGL(gemm_reduce, dim3(N / 256, M / (TILES * TCOLS)), dim3(256), 0, stream,
                     d0, Bt, best01, best10, N);
  hipLaunchKernelGGL(finalize, dim3(N / 256), dim3(256), 0, stream, best01, best10, out, N);
}

// Round 10
// 103.695 us; speedup vs baseline: 1.2189x; 1.1968x over previous
//
#include <hip/hip_runtime.h>
#include <hip/hip_bf16.h>

typedef __attribute__((ext_vector_type(8))) short short8;   // 8 bf16 (MFMA A/B frag)
typedef __attribute__((ext_vector_type(4))) float floatx4;  // MFMA C/D frag
typedef unsigned int u32;

#define D_DIM 256
#define TCOLS 32      // B-tile width -> dbuf LDS = 2*32*256*2 = 32768 B
#define TILES 16      // tiles per block -> 512 cols/block -> grid 32x16 = 512 blocks
#define IDX_BITS 0x1FFFu      // 13-bit index payload (N=M=8192)
#define VAL_MASK 0xFFFFE000u  // truncated value bits (sim+2 positive -> raw bits monotone)

// ---------- helpers ----------

__device__ inline unsigned short f2bf_rne(float f) {
  u32 u = __float_as_uint(f);
  u32 r = (u + 0x7FFFu + ((u >> 16) & 1u)) >> 16;
  return (unsigned short)r;
}

__device__ inline u32 umax(u32 a, u32 b) { return a > b ? a : b; }

__device__ inline void async_ld16(const void* g, void* l) {
  __builtin_amdgcn_global_load_lds((const __attribute__((address_space(1))) void*)g,
                                   (__attribute__((address_space(3))) void*)l, 16, 0, 0);
}

// ---------- kernels ----------

// B only: [256][8192] f32 -> [8192][256] bf16. Coalesced 256B reads/wave,
// 16B short8 stores. Folds best-array init. (A is cast inline in the GEMM.)
__global__ __launch_bounds__(256) void transpose_cast(const float* __restrict__ src,
                                                      unsigned short* __restrict__ dst, int C,
                                                      u32* __restrict__ best, int init_n) {
  const int tid = threadIdx.x;
  const int d = blockIdx.x * 64 + (tid & 63);     // descriptor index
  const int chunk = blockIdx.y * 4 + (tid >> 6);  // 8-feature chunk, 0..31
  const int f0 = chunk * 8;
  float v[8];
#pragma unroll
  for (int u = 0; u < 8; ++u) v[u] = src[(size_t)(f0 + u) * C + d];
  short8 o;
#pragma unroll
  for (int u = 0; u < 8; ++u) o[u] = (short)f2bf_rne(v[u]);
  *(short8*)(dst + (size_t)d * D_DIM + f0) = o;
  if (blockIdx.y == 0) {
    int i = blockIdx.x * 256 + tid;  // 128 x 256 = 32768 >= 16384
    if (i < init_n) best[i] = 0u;
  }
}

// Full-K-in-registers GEMM + fused argmax. 256 threads, 4 waves x 64 rows.
// LDS = 32 KB total (TCOLS=32 dbuf): small enough that the HW scheduler can
// co-schedule 2+ blocks/CU (evidence: never co-schedules at >=64 KB — R3/R6/
// R7/R9; ~3 blocks at 34.8 KB per m97/m114). 2 blocks/CU -> 2 waves/SIMD
// with the relaxed (256,1) allocation (~208 regs/wave, no cap -> no spill).
// acc init = +2.0: outputs sim+2 in [1,3), positive -> raw IEEE bits
// monotone under unsigned compare -> no fmap in the epilogue.
__global__ __launch_bounds__(256, 1) void gemm_reduce(const float* __restrict__ A,
                                                      const unsigned short* __restrict__ Bt,
                                                      u32* __restrict__ best01,
                                                      u32* __restrict__ best10,
                                                      int N) {
  __shared__ alignas(16) unsigned short sB[2][TCOLS * D_DIM];  // 2 x 16 KB = 32768 B

  const int tid  = threadIdx.x;
  const int wave = tid >> 6;
  const int lane = tid & 63;
  const int quad = lane >> 4;
  const int l15  = lane & 15;
  const int n0   = blockIdx.x * 256;
  const int mg0  = blockIdx.y * (TILES * TCOLS);
  const int rbase = n0 + wave * 64;   // 64 rows per wave

  // stage B tile 0 into buf 0 (LDS dest = uniform base + tid*16 — required)
  {
    const unsigned short* src = Bt + (size_t)mg0 * D_DIM;
#pragma unroll
    for (int c = 0; c < 4; ++c) {     // 1024 slots / 256 threads
      int slot = c * 256 + tid;
      int r = slot >> 5, cc = slot & 31;
      int ccg = (cc & 24) | ((cc ^ r) & 7);  // XOR-swizzle spreads frag-read banks
      async_ld16(src + (size_t)r * D_DIM + ccg * 8, (unsigned short*)sB[0] + slot * 8);
    }
  }

  // A fragments: wave's 64 rows x full K=256 from f32 [256][N], cast to bf16.
  // Per (t,kc,u): 16 lanes (l15) read 16 consecutive f32 = 64B segments.
  short8 af[4][8];
#pragma unroll
  for (int t = 0; t < 4; ++t)
#pragma unroll
    for (int kc = 0; kc < 8; ++kc) {
      const int row = rbase + t * 16 + l15;
      const int kb = kc * 32 + quad * 8;
      short8 o;
#pragma unroll
      for (int u = 0; u < 8; ++u)
        o[u] = (short)f2bf_rne(A[(size_t)(kb + u) * N + row]);
      af[t][kc] = o;
    }

  u32 rbk[16];  // running row-argmax keys (16 rows per lane)
#pragma unroll
  for (int s = 0; s < 16; ++s) rbk[s] = 0u;

  __syncthreads();  // drains vmcnt: B0 staged

  for (int mt = 0; mt < TILES; ++mt) {
    const int m0 = mg0 + mt * TCOLS;
    if (mt + 1 < TILES) {  // prefetch next B tile — latency hides under MFMA
      const unsigned short* src = Bt + (size_t)(m0 + TCOLS) * D_DIM;
      unsigned short* dstb = (unsigned short*)sB[(mt + 1) & 1];
#pragma unroll
      for (int c = 0; c < 4; ++c) {
        int slot = c * 256 + tid;
        int r = slot >> 5, cc = slot & 31;
        int ccg = (cc & 24) | ((cc ^ r) & 7);
        async_ld16(src + (size_t)r * D_DIM + ccg * 8, dstb + slot * 8);
      }
    }

    floatx4 acc[4][2];
#pragma unroll
    for (int i = 0; i < 4; ++i)
#pragma unroll
      for (int j = 0; j < 2; ++j)
        acc[i][j] = (floatx4){2.0f, 2.0f, 2.0f, 2.0f};  // bias: outputs = sim+2 > 0

    const unsigned short* sb = (const unsigned short*)sB[mt & 1];
#pragma unroll
    for (int kc = 0; kc < 8; ++kc) {
      short8 bfr[2];
#pragma unroll
      for (int j = 0; j < 2; ++j) {
        int c2 = j * 16 + l15;
        int ch = kc * 4 + quad;
        int chg = (ch & 24) | ((ch ^ c2) & 7);  // un-swizzle
        bfr[j] = *(const short8*)(sb + c2 * D_DIM + chg * 8);
      }
#pragma unroll
      for (int i = 0; i < 4; ++i)
#pragma unroll
        for (int j = 0; j < 2; ++j)
          acc[i][j] = __builtin_amdgcn_mfma_f32_16x16x32_bf16(af[i][kc], bfr[j], acc[i][j], 0, 0, 0);
    }

    // ---- epilogue. C/D map: col = j*16 + l15, row = i*16 + quad*4 + r
    u32 cb[2] = {0u, 0u};
    u32 colpay[2];
#pragma unroll
    for (int j = 0; j < 2; ++j) colpay[j] = (~(u32)(m0 + j * 16 + l15)) & IDX_BITS;
#pragma unroll
    for (int i = 0; i < 4; ++i)
#pragma unroll
      for (int r = 0; r < 4; ++r) {
        u32 rowpay = (~(u32)(rbase + i * 16 + quad * 4 + r)) & IDX_BITS;
        u32 rb = rbk[i * 4 + r];
#pragma unroll
        for (int j = 0; j < 2; ++j) {
          u32 u = __float_as_uint(acc[i][j][r]) & VAL_MASK;  // positive -> monotone
          rb = umax(rb, u | colpay[j]);
          cb[j] = umax(cb[j], u | rowpay);
        }
        rbk[i * 4 + r] = rb;
      }
    // col-argmax: butterfly over the 4 quads, then DIRECT global atomics
#pragma unroll
    for (int j = 0; j < 2; ++j) {
      u32 b = cb[j];
      b = umax(b, (u32)__shfl_xor((int)b, 16, 64));
      b = umax(b, (u32)__shfl_xor((int)b, 32, 64));
      if (quad == 0) atomicMax(&best10[m0 + j * 16 + l15], b);
    }
    __syncthreads();  // all ds_reads of sb done; vmcnt drained -> next B ready
  }

  // ---- final row reduction: butterfly over l15, one atomic per row
#pragma unroll
  for (int i = 0; i < 4; ++i)
#pragma unroll
    for (int r = 0; r < 4; ++r) {
      u32 b = rbk[i * 4 + r];
      b = umax(b, (u32)__shfl_xor((int)b, 1, 64));
      b = umax(b, (u32)__shfl_xor((int)b, 2, 64));
      b = umax(b, (u32)__shfl_xor((int)b, 4, 64));
      b = umax(b, (u32)__shfl_xor((int)b, 8, 64));
      if (l15 == 0) atomicMax(&best01[rbase + i * 16 + quad * 4 + r], b);
    }
}

__global__ void finalize(const u32* __restrict__ best01, const u32* __restrict__ best10,
                         float* __restrict__ out, int N) {
  int n = blockIdx.x * blockDim.x + threadIdx.x;
  if (n >= N) return;
  u32 k = best01[n];
  int idx01 = (int)((~k) & IDX_BITS);
  float sim = __uint_as_float(k & VAL_MASK) - 2.0f;  // undo +2 bias
  int idx10 = (int)((~best10[idx01]) & IDX_BITS);
  float dist = 2.0f - 2.0f * sim;             // squared L2 for unit vectors
  bool ok = (idx10 == n) && (dist <= 0.64f);  // mutual NN + thresh^2
  out[n]     = ok ? (float)idx01 : -1.0f;
  out[N + n] = ok ? 1.5f - sim : 0.0f;        // (dist+1)/2
}

// ---------- launcher ----------

extern "C" void kernel_launch(void* const* d_in, const int* in_sizes, int n_in,
                              void* d_out, int out_size, void* d_ws, size_t ws_size,
                              hipStream_t stream) {
  (void)n_in; (void)out_size; (void)ws_size;
  const float* d0 = (const float*)d_in[0];  // [256][N]
  const float* d1 = (const float*)d_in[1];  // [256][M]
  const int N = in_sizes[0] / D_DIM;        // 8192
  const int M = in_sizes[1] / D_DIM;        // 8192

  u32* best01 = (u32*)d_ws;                            // N u32
  u32* best10 = best01 + N;                            // M u32
  unsigned short* Bt = (unsigned short*)(best10 + M);  // [M][256] bf16
  float* out = (float*)d_out;

  hipLaunchKernelGGL(transpose_cast, dim3(M / 64, 8), dim3(256), 0, stream,
                     d1, Bt, M, best01, N + M);
  hipLaunchKernelGGL(gemm_reduce, dim3(N / 256, M / (TILES * TCOLS)), dim3(256), 0, stream,
                     d0, Bt, best01, best10, N);
  hipLaunchKernelGGL(finalize, dim3(N / 256), dim3(256), 0, stream, best01, best10, out, N);
}